// Round 2
// baseline (537.574 us; speedup 1.0000x reference)
//
#include <hip/hip_runtime.h>
#include <math.h>

#define TPB 512
static constexpr int N0  = 64;   // nodes per graph
static constexpr int H   = 128;  // hidden
static constexpr int XLD = 132;  // LDS row stride for feature tiles (16B aligned, bank-skewed)
static constexpr int ALD = 65;   // LDS row stride for adjacency

struct alignas(16) Shm {
  float adjS[N0 * ALD];   // 16640 B  current adjacency (raw, no self loops)
  float Xs[N0 * XLD];     // 33792 B  ping buffer
  float Zs[32 * XLD];     // 16896 B  pong buffer (z1 as [64][36]; MLP partials)
  float rbuf[2 * H];      // readout accumulator [max(128) | mean(128)]
  float uu[N0], vv[N0], sv[N0], tv[N0], dinv[N0];
  float h1[H];
  int   sel[N0];
};

template<int W>
__device__ __forceinline__ float redsum(float v) {
  #pragma unroll
  for (int m = W >> 1; m; m >>= 1) v += __shfl_xor(v, m, 64);
  return v;
}

// z[i][k] = dinv[i] * sum_j (adj[i][j] + delta_ij) * dinv[j] * x[j][k]
template<int NN, int NCH, int KCH>
__device__ __forceinline__ void norm_agg(const Shm& sh, const float* x, int xld,
                                         float* z, int zld, int tid) {
  for (int it = tid; it < NN * NCH; it += TPB) {
    int i = it & (NN - 1);
    int g = it / NN;
    const float* arow = &sh.adjS[i * ALD];
    float acc[KCH];
    #pragma unroll
    for (int c = 0; c < KCH; ++c) acc[c] = 0.f;
    for (int j = 0; j < NN; ++j) {
      float a = (arow[j] + ((j == i) ? 1.f : 0.f)) * sh.dinv[j];
      const float* xp = x + j * xld + g * KCH;
      #pragma unroll
      for (int c = 0; c < KCH; c += 4) {
        float4 xv = *(const float4*)(xp + c);
        acc[c]     += a * xv.x; acc[c + 1] += a * xv.y;
        acc[c + 2] += a * xv.z; acc[c + 3] += a * xv.w;
      }
    }
    float di = sh.dinv[i];
    #pragma unroll
    for (int c = 0; c < KCH; c += 4) {
      float4 r = make_float4(acc[c] * di, acc[c + 1] * di, acc[c + 2] * di, acc[c + 3] * di);
      *(float4*)(z + i * zld + g * KCH + c) = r;
    }
  }
}

// out[i][f] = relu(sum_k z[i][k] * W[k][f] + b[f]); 512 thr = 4 row-groups x 128 f
template<int R, int K, int KREAL>
__device__ __forceinline__ void gemm_bias_relu(const float* z, int zld,
    const float* __restrict__ Wg, const float* __restrict__ bg,
    float* out, int old_, int tid) {
  constexpr int NR = R / 4;
  int f  = tid & (H - 1);
  int r0 = (tid >> 7) * NR;
  float acc[NR];
  float bf = bg[f];
  #pragma unroll
  for (int r = 0; r < NR; ++r) acc[r] = bf;
  #pragma unroll
  for (int kt = 0; kt < K; kt += 32) {
    const int kn = (K - kt < 32) ? (K - kt) : 32;
    float w[32];
    #pragma unroll
    for (int k = 0; k < 32; ++k)
      w[k] = (k < kn && (kt + k) < KREAL) ? Wg[(kt + k) * H + f] : 0.f;
    #pragma unroll
    for (int r = 0; r < NR; ++r) {
      const float* zr = z + (r0 + r) * zld + kt;
      float a0 = 0.f, a1 = 0.f, a2 = 0.f, a3 = 0.f;
      #pragma unroll
      for (int k = 0; k < 32; k += 4) {
        if (k < kn) {
          float4 zv = *(const float4*)(zr + k);
          a0 += zv.x * w[k];     a1 += zv.y * w[k + 1];
          a2 += zv.z * w[k + 2]; a3 += zv.w * w[k + 3];
        }
      }
      acc[r] += (a0 + a1) + (a2 + a3);
    }
  }
  #pragma unroll
  for (int r = 0; r < NR; ++r)
    out[(r0 + r) * old_ + f] = fmaxf(acc[r], 0.f);
}

// SAGPool(NN->KK) + filtered adjacency in place + next-stage dinv + readout accum.
template<int NN, int KK, int UVP, int SCP, bool DODINV>
__device__ __forceinline__ void sag_pool_readout(Shm& sh,
    const float* x, float* xn,
    const float* __restrict__ wl, const float* __restrict__ blp,
    const float* __restrict__ wr, int tid) {
  { // u[j]=x[j].wl, v[j]=x[j].wr  — 2*NN dots, UVP lanes each (2*NN*UVP == TPB)
    int dot = tid / UVP, p = tid % UVP;
    int j = dot >> 1;
    const float* wp = (dot & 1) ? wr : wl;
    constexpr int CH = H / UVP;
    const float* xr = x + j * XLD + p * CH;
    const float* wq = wp + p * CH;
    float a = 0.f;
    #pragma unroll
    for (int k = 0; k < CH; k += 4) {
      float4 xv = *(const float4*)(xr + k);
      float4 wv = *(const float4*)(wq + k);
      a += xv.x * wv.x + xv.y * wv.y + xv.z * wv.z + xv.w * wv.w;
    }
    a = redsum<UVP>(a);
    if (p == 0) { if (dot & 1) sh.vv[j] = a; else sh.uu[j] = a; }
  }
  __syncthreads();
  // s[i] = sum_j adj[i][j]*u[j] + bl + v[i]  — SCP lanes per row
  if (tid < NN * SCP) {
    int i = tid / SCP, p = tid % SCP;
    constexpr int CH = NN / SCP;
    float a = 0.f;
    #pragma unroll
    for (int c = 0; c < CH; ++c) { int j = p * CH + c; a += sh.adjS[i * ALD + j] * sh.uu[j]; }
    a = redsum<SCP>(a);
    if (p == 0) sh.sv[i] = a + blp[0] + sh.vv[i];
  }
  __syncthreads();
  // exact stable top-k via rank counting
  if (tid < NN) {
    float si = sh.sv[tid];
    int rank = 0;
    for (int j = 0; j < NN; ++j) {
      float sj = sh.sv[j];
      rank += (sj > si || (sj == si && j < tid)) ? 1 : 0;
    }
    if (rank < KK) { sh.sel[rank] = tid; sh.tv[rank] = tanhf(si); }
  }
  __syncthreads();
  // gather x_next = x[sel] * tanh(s[sel])
  for (int e = tid; e < KK * H; e += TPB) {
    int r = e >> 7, f = e & (H - 1);
    xn[r * XLD + f] = x[sh.sel[r] * XLD + f] * sh.tv[r];
  }
  // filtered adjacency: stage in regs, barrier, write back; fuse next dinv
  constexpr int NE = (KK * KK + TPB - 1) / TPB;
  float areg[NE];
  #pragma unroll
  for (int q = 0; q < NE; ++q) {
    int e = tid + q * TPB;
    if (e < KK * KK)
      areg[q] = sh.adjS[sh.sel[e / KK] * ALD + sh.sel[e & (KK - 1)]];
  }
  __syncthreads();
  #pragma unroll
  for (int q = 0; q < NE; ++q) {
    int e = tid + q * TPB;
    if (e < KK * KK)
      sh.adjS[(e / KK) * ALD + (e & (KK - 1))] = areg[q];
  }
  if (DODINV) {
    #pragma unroll
    for (int q = 0; q < NE; ++q) {
      int e = tid + q * TPB;
      float a = (e < KK * KK) ? areg[q] : 0.f;
      a = redsum<(KK < 64 ? KK : 64)>(a);
      if (e < KK * KK && (e & (KK - 1)) == 0)
        sh.dinv[e / KK] = rsqrtf(1.f + a);
    }
  }
  // readout: cat(max, mean) over KK rows, accumulated
  if (tid < H) {
    float m = -INFINITY, s = 0.f;
    #pragma unroll
    for (int r = 0; r < KK; ++r) {
      float v = xn[r * XLD + tid];
      m = fmaxf(m, v); s += v;
    }
    sh.rbuf[tid]     += m;
    sh.rbuf[H + tid] += s * (1.f / KK);
  }
  __syncthreads();
}

__global__ __launch_bounds__(TPB, 4) void sagpool_fused(
    const int* __restrict__ aa, const float* __restrict__ pos,
    const float* __restrict__ cdr, const float* __restrict__ adjG,
    const float* __restrict__ emb,
    const float* __restrict__ W1, const float* __restrict__ b1,
    const float* __restrict__ p1wl, const float* __restrict__ p1bl, const float* __restrict__ p1wr,
    const float* __restrict__ W2, const float* __restrict__ b2,
    const float* __restrict__ p2wl, const float* __restrict__ p2bl, const float* __restrict__ p2wr,
    const float* __restrict__ W3, const float* __restrict__ b3,
    const float* __restrict__ p3wl, const float* __restrict__ p3bl, const float* __restrict__ p3wr,
    const float* __restrict__ mW1, const float* __restrict__ mb1,
    const float* __restrict__ mW2, const float* __restrict__ mb2,
    const float* __restrict__ mW3, const float* __restrict__ mb3,
    float* __restrict__ out)
{
  __shared__ Shm sh;
  const int b   = blockIdx.x;
  const int tid = threadIdx.x;

  if (tid < 2 * H) sh.rbuf[tid] = 0.f;

  // load adjacency [64][64] -> adjS (stride 65) with fused row-sum -> dinv
  {
    const float* src = adjG + (size_t)b * (N0 * N0);
    int e1 = tid;            // rows 0..31 (16 lanes per row)
    int e2 = tid + TPB;      // rows 32..63
    int r1 = e1 >> 4, c1 = (e1 & 15) * 4;
    int r2 = e2 >> 4, c2 = (e2 & 15) * 4;
    float4 v1 = *(const float4*)(src + r1 * N0 + c1);
    float4 v2 = *(const float4*)(src + r2 * N0 + c2);
    float* d1 = &sh.adjS[r1 * ALD + c1];
    float* d2 = &sh.adjS[r2 * ALD + c2];
    d1[0] = v1.x; d1[1] = v1.y; d1[2] = v1.z; d1[3] = v1.w;
    d2[0] = v2.x; d2[1] = v2.y; d2[2] = v2.z; d2[3] = v2.w;
    float s1 = redsum<16>(v1.x + v1.y + v1.z + v1.w);
    float s2 = redsum<16>(v2.x + v2.y + v2.z + v2.w);
    if ((tid & 15) == 0) {
      sh.dinv[r1] = rsqrtf(1.f + s1);
      sh.dinv[r2] = rsqrtf(1.f + s2);
    }
  }
  // build x = [emb[aa] | pos | is_cdr3 | 0 0] into Xs cols 0..35
  for (int e = tid; e < N0 * 36; e += TPB) {
    int j = e / 36, k = e - j * 36;
    int node = b * N0 + j;
    float v;
    if (k < 32)       v = emb[aa[node] * 32 + k];
    else if (k == 32) v = pos[node];
    else if (k == 33) v = cdr[node];
    else              v = 0.f;
    sh.Xs[j * XLD + k] = v;
  }
  __syncthreads();

  // ---- stage 1: GCN(34->128) on 64 nodes, pool 64->32 ----
  norm_agg<64, 9, 4>(sh, sh.Xs, XLD, sh.Zs, 36, tid);
  __syncthreads();
  gemm_bias_relu<64, 36, 34>(sh.Zs, 36, W1, b1, sh.Xs, XLD, tid);
  __syncthreads();
  sag_pool_readout<64, 32, 4, 8, true>(sh, sh.Xs, sh.Zs, p1wl, p1bl, p1wr, tid);

  // ---- stage 2: GCN(128->128) on 32 nodes, pool 32->16 ----
  norm_agg<32, 16, 8>(sh, sh.Zs, XLD, sh.Xs, XLD, tid);
  __syncthreads();
  gemm_bias_relu<32, 128, 128>(sh.Xs, XLD, W2, b2, sh.Zs, XLD, tid);
  __syncthreads();
  sag_pool_readout<32, 16, 8, 16, true>(sh, sh.Zs, sh.Xs, p2wl, p2bl, p2wr, tid);

  // ---- stage 3: GCN(128->128) on 16 nodes, pool 16->8 ----
  norm_agg<16, 16, 8>(sh, sh.Xs, XLD, sh.Zs, XLD, tid);
  __syncthreads();
  gemm_bias_relu<16, 128, 128>(sh.Zs, XLD, W3, b3, sh.Xs, XLD, tid);
  __syncthreads();
  sag_pool_readout<16, 8, 16, 16, false>(sh, sh.Xs, sh.Zs, p3wl, p3bl, p3wr, tid);

  // ---- MLP head on rbuf[256] ----
  { // h1 partials: 128 f x 4 k-parts -> Zs[0..511]
    int f = tid & (H - 1), p = tid >> 7;
    const int base = p * 64;
    float a = 0.f;
    for (int k = 0; k < 64; ++k) a += sh.rbuf[base + k] * mW1[(base + k) * H + f];
    sh.Zs[p * H + f] = a;
  }
  __syncthreads();
  if (tid < H) {
    float a = mb1[tid] + sh.Zs[tid] + sh.Zs[H + tid] + sh.Zs[2 * H + tid] + sh.Zs[3 * H + tid];
    sh.h1[tid] = fmaxf(a, 0.f);
  }
  __syncthreads();
  { // h2 partials: 64 o x 8 k-parts -> Zs[0..511]
    int o = tid & 63, p = tid >> 6;
    const int base = p * 16;
    float a = 0.f;
    #pragma unroll
    for (int k = 0; k < 16; ++k) a += sh.h1[base + k] * mW2[(base + k) * 64 + o];
    sh.Zs[p * 64 + o] = a;
  }
  __syncthreads();
  if (tid < 64) {
    float a = 0.f;
    #pragma unroll
    for (int p = 0; p < 8; ++p) a += sh.Zs[p * 64 + tid];
    a = fmaxf(a + mb2[tid], 0.f);
    float v = a * mW3[tid];
    v = redsum<64>(v);
    if (tid == 0) out[b] = v + mb3[0];
  }
}

extern "C" void kernel_launch(void* const* d_in, const int* in_sizes, int n_in,
                              void* d_out, int out_size, void* d_ws, size_t ws_size,
                              hipStream_t stream) {
  (void)n_in; (void)d_ws; (void)ws_size; (void)out_size;
  const int*   aa   = (const int*)  d_in[0];
  const float* pos  = (const float*)d_in[1];
  const float* cdr  = (const float*)d_in[2];
  const float* adj  = (const float*)d_in[3];
  const float* emb  = (const float*)d_in[4];
  const float* W1   = (const float*)d_in[5];
  const float* b1   = (const float*)d_in[6];
  const float* p1wl = (const float*)d_in[7];
  const float* p1bl = (const float*)d_in[8];
  const float* p1wr = (const float*)d_in[9];
  const float* W2   = (const float*)d_in[10];
  const float* b2   = (const float*)d_in[11];
  const float* p2wl = (const float*)d_in[12];
  const float* p2bl = (const float*)d_in[13];
  const float* p2wr = (const float*)d_in[14];
  const float* W3   = (const float*)d_in[15];
  const float* b3   = (const float*)d_in[16];
  const float* p3wl = (const float*)d_in[17];
  const float* p3bl = (const float*)d_in[18];
  const float* p3wr = (const float*)d_in[19];
  const float* mW1  = (const float*)d_in[20];
  const float* mb1  = (const float*)d_in[21];
  const float* mW2  = (const float*)d_in[22];
  const float* mb2  = (const float*)d_in[23];
  const float* mW3  = (const float*)d_in[24];
  const float* mb3  = (const float*)d_in[25];
  float* out = (float*)d_out;

  const int B = in_sizes[0] / N0;  // 4096
  hipLaunchKernelGGL(sagpool_fused, dim3(B), dim3(TPB), 0, stream,
                     aa, pos, cdr, adj, emb,
                     W1, b1, p1wl, p1bl, p1wr,
                     W2, b2, p2wl, p2bl, p2wr,
                     W3, b3, p3wl, p3bl, p3wr,
                     mW1, mb1, mW2, mb2, mW3, mb3, out);
}